// Round 1
// baseline (1084.388 us; speedup 1.0000x reference)
//
#include <hip/hip_runtime.h>

static inline size_t align256(size_t x) { return (x + 255) & ~size_t(255); }

// ---------------- build: degree histogram ----------------
__global__ void k_deg(const int* __restrict__ ei, int* __restrict__ deg, int E) {
    int e = blockIdx.x * blockDim.x + threadIdx.x;
    if (e < E) atomicAdd(&deg[ei[E + e]], 1);   // dst = row 1
}

__global__ void k_dinv(const int* __restrict__ deg, float* __restrict__ dinv, int n) {
    int i = blockIdx.x * blockDim.x + threadIdx.x;
    if (i < n) dinv[i] = rsqrtf((float)deg[i] + 1.0f);  // +1 = self loop
}

// ---------------- build: exclusive scan (3 kernels) ----------------
// scan1: per-block (1024 elems) exclusive scan into row_ptr, block totals to bsum
__global__ void k_scan1(const int* __restrict__ deg, int* __restrict__ ex,
                        int* __restrict__ bsum, int n) {
    __shared__ int lds[256];
    int t = threadIdx.x;
    int base = blockIdx.x * 1024 + t * 4;
    int v0 = (base + 0 < n) ? deg[base + 0] : 0;
    int v1 = (base + 1 < n) ? deg[base + 1] : 0;
    int v2 = (base + 2 < n) ? deg[base + 2] : 0;
    int v3 = (base + 3 < n) ? deg[base + 3] : 0;
    int s = v0 + v1 + v2 + v3;
    lds[t] = s;
    __syncthreads();
    for (int off = 1; off < 256; off <<= 1) {
        int x = (t >= off) ? lds[t - off] : 0;
        __syncthreads();
        lds[t] += x;
        __syncthreads();
    }
    int excl = lds[t] - s;
    if (t == 255) bsum[blockIdx.x] = lds[255];
    if (base + 0 < n) ex[base + 0] = excl; excl += v0;
    if (base + 1 < n) ex[base + 1] = excl; excl += v1;
    if (base + 2 < n) ex[base + 2] = excl; excl += v2;
    if (base + 3 < n) ex[base + 3] = excl;
}

// scan2: single block, exclusive scan of block totals (nb <= 256)
__global__ void k_scan2(int* __restrict__ bsum, int nb) {
    __shared__ int lds[256];
    int t = threadIdx.x;
    int s = (t < nb) ? bsum[t] : 0;
    lds[t] = s;
    __syncthreads();
    for (int off = 1; off < 256; off <<= 1) {
        int x = (t >= off) ? lds[t - off] : 0;
        __syncthreads();
        lds[t] += x;
        __syncthreads();
    }
    if (t < nb) bsum[t] = lds[t] - s;
}

// scan3: add block offsets; copy to cursor; write row_ptr[n]=E
__global__ void k_scan3(int* __restrict__ row_ptr, int* __restrict__ cursor,
                        const int* __restrict__ bsum, int n, int E) {
    int i = blockIdx.x * blockDim.x + threadIdx.x;
    if (i < n) {
        int v = row_ptr[i] + bsum[i >> 10];
        row_ptr[i] = v;
        cursor[i] = v;
    }
    if (i == n) row_ptr[n] = E;
}

// ---------------- build: CSR fill ----------------
__global__ void k_fill(const int* __restrict__ ei, int* __restrict__ cursor,
                       int* __restrict__ col, int E) {
    int e = blockIdx.x * blockDim.x + threadIdx.x;
    if (e >= E) return;
    int s = ei[e];          // src = row 0
    int d = ei[E + e];      // dst = row 1
    int pos = atomicAdd(&cursor[d], 1);
    col[pos] = s;
}

// ---------------- feature transforms (pre-scaled by dinv) ----------------
// g1[n,f] = (x[n,0]*W1[0,f] + x[n,1]*W1[1,f]) * dinv[n]
__global__ void k_t1(const float* __restrict__ x, const float* __restrict__ W1,
                     const float* __restrict__ dinv, float* __restrict__ g1, int n) {
    int i = blockIdx.x * blockDim.x + threadIdx.x;
    int node = i >> 4, f = i & 15;
    if (node >= n) return;
    float x0 = x[node * 2 + 0], x1 = x[node * 2 + 1];
    g1[i] = (x0 * W1[f] + x1 * W1[16 + f]) * dinv[node];
}

// g2[n,of] = (sum_k h1[n,k]*W2[k,of]) * dinv[n]
__global__ void k_t2(const float* __restrict__ h1, const float* __restrict__ W2,
                     const float* __restrict__ dinv, float* __restrict__ g2, int n) {
    int i = blockIdx.x * blockDim.x + threadIdx.x;
    int node = i >> 5, of = i & 31;
    if (node >= n) return;
    const float* hr = h1 + node * 16;
    float acc = 0.f;
#pragma unroll
    for (int k = 0; k < 16; ++k) acc += hr[k] * W2[k * 32 + of];
    g2[i] = acc * dinv[node];
}

// ---------------- GCN aggregation: out[n,f] = relu(dinv[n]*(sum g[col]+g[n]) + b[f])
template <int F>
__global__ __launch_bounds__(256) void k_conv(const int* __restrict__ row_ptr,
                                              const int* __restrict__ col,
                                              const float* __restrict__ g,
                                              const float* __restrict__ dinv,
                                              const float* __restrict__ bias,
                                              float* __restrict__ out, int n) {
    constexpr int NPB = 256 / F;
    int node = blockIdx.x * NPB + threadIdx.x / F;
    int f = threadIdx.x & (F - 1);
    if (node >= n) return;
    int rs = row_ptr[node], re = row_ptr[node + 1];
    float acc = 0.f;
    int e = rs;
    for (; e + 4 <= re; e += 4) {
        int s0 = col[e], s1 = col[e + 1], s2 = col[e + 2], s3 = col[e + 3];
        float v0 = g[s0 * F + f];
        float v1 = g[s1 * F + f];
        float v2 = g[s2 * F + f];
        float v3 = g[s3 * F + f];
        acc += (v0 + v1) + (v2 + v3);
    }
    for (; e < re; ++e) acc += g[col[e] * F + f];
    acc += g[node * F + f];                     // self loop
    float v = dinv[node] * acc + bias[f];
    out[node * F + f] = fmaxf(v, 0.f);
}

// ---------------- pooling: graph segment starts from sorted batch ----------------
__global__ void k_starts(const int* __restrict__ batch, int* __restrict__ start,
                         int n, int G) {
    int i = blockIdx.x * blockDim.x + threadIdx.x;
    if (i >= n) return;
    int b = batch[i];
    int bp = (i == 0) ? -1 : batch[i - 1];
    for (int k = bp + 1; k <= b; ++k) start[k] = i;
    if (i == n - 1) {
        for (int k = b + 1; k <= G; ++k) start[k] = n;
    }
}

// ---------------- per-graph mean pool + fused MLP head ----------------
__global__ __launch_bounds__(256) void k_pool_mlp(const float* __restrict__ h2,
                                                  const int* __restrict__ start,
                                                  const float* __restrict__ Wfc1,
                                                  const float* __restrict__ bfc1,
                                                  const float* __restrict__ Wfc2,
                                                  const float* __restrict__ bfc2,
                                                  float* __restrict__ out, int G) {
    __shared__ float lds[256];
    __shared__ float pooled[32];
    __shared__ float hidden[16];
    int g = blockIdx.x;
    if (g >= G) return;
    int s = start[g], e = start[g + 1];
    int r = threadIdx.x >> 5;       // 0..7
    int f = threadIdx.x & 31;       // 0..31
    float acc = 0.f;
    for (int i = s + r; i < e; i += 8) acc += h2[(size_t)i * 32 + f];
    lds[f * 8 + r] = acc;
    __syncthreads();
    if (threadIdx.x < 32) {
        float t = 0.f;
#pragma unroll
        for (int k = 0; k < 8; ++k) t += lds[threadIdx.x * 8 + k];
        float cnt = (float)(e - s);
        pooled[threadIdx.x] = t / fmaxf(cnt, 1.0f);
    }
    __syncthreads();
    if (threadIdx.x < 16) {
        float a = bfc1[threadIdx.x];
#pragma unroll
        for (int i = 0; i < 32; ++i) a += pooled[i] * Wfc1[i * 16 + threadIdx.x];
        hidden[threadIdx.x] = fmaxf(a, 0.f);
    }
    __syncthreads();
    if (threadIdx.x == 0) {
        float a = bfc2[0];
#pragma unroll
        for (int j = 0; j < 16; ++j) a += hidden[j] * Wfc2[j];
        out[g] = a;
    }
}

extern "C" void kernel_launch(void* const* d_in, const int* in_sizes, int n_in,
                              void* d_out, int out_size, void* d_ws, size_t ws_size,
                              hipStream_t stream) {
    const float* x     = (const float*)d_in[0];
    const int*   ei    = (const int*)d_in[1];
    const int*   batch = (const int*)d_in[2];
    const float* W1    = (const float*)d_in[3];
    const float* b1    = (const float*)d_in[4];
    const float* W2    = (const float*)d_in[5];
    const float* b2    = (const float*)d_in[6];
    const float* Wfc1  = (const float*)d_in[7];
    const float* bfc1  = (const float*)d_in[8];
    const float* Wfc2  = (const float*)d_in[9];
    const float* bfc2  = (const float*)d_in[10];
    float* out = (float*)d_out;

    const int N = in_sizes[0] / 2;      // 200000
    const int E = in_sizes[1] / 2;      // 6400000
    const int G = out_size;             // 1000

    // ---- workspace layout ----
    char* ws = (char*)d_ws;
    size_t off = 0;
    int*   deg     = (int*)(ws + off);  off += align256((size_t)N * 4);
    float* dinv    = (float*)(ws + off); off += align256((size_t)N * 4);
    int*   row_ptr = (int*)(ws + off);  off += align256((size_t)(N + 1) * 4);
    int*   cursor  = (int*)(ws + off);  off += align256((size_t)N * 4);
    int*   bsum    = (int*)(ws + off);  off += align256(256 * 4);
    int*   start   = (int*)(ws + off);  off += align256((size_t)(G + 1) * 4);
    int*   col     = (int*)(ws + off);  off += align256((size_t)E * 4);
    float* g2      = (float*)(ws + off); off += align256((size_t)N * 32 * 4);
    float* g1      = (float*)(ws + off); // N*16 floats
    float* h1      = (float*)(ws + off + (size_t)N * 16 * 4);
    float* h2      = g1;                 // aliases g1|h1 (both dead when h2 written)
    // total ~80 MB

    const int BS = 256;
    const int NB_SCAN = (N + 1023) / 1024;   // 196

    hipMemsetAsync(deg, 0, (size_t)N * 4, stream);

    k_deg<<<(E + BS - 1) / BS, BS, 0, stream>>>(ei, deg, E);
    k_dinv<<<(N + BS - 1) / BS, BS, 0, stream>>>(deg, dinv, N);

    k_scan1<<<NB_SCAN, 256, 0, stream>>>(deg, row_ptr, bsum, N);
    k_scan2<<<1, 256, 0, stream>>>(bsum, NB_SCAN);
    k_scan3<<<(N + 1 + BS - 1) / BS, BS, 0, stream>>>(row_ptr, cursor, bsum, N, E);

    k_fill<<<(E + BS - 1) / BS, BS, 0, stream>>>(ei, cursor, col, E);

    k_t1<<<((size_t)N * 16 + BS - 1) / BS, BS, 0, stream>>>(x, W1, dinv, g1, N);
    k_conv<16><<<(N + 15) / 16, 256, 0, stream>>>(row_ptr, col, g1, dinv, b1, h1, N);
    k_t2<<<((size_t)N * 32 + BS - 1) / BS, BS, 0, stream>>>(h1, W2, dinv, g2, N);
    k_conv<32><<<(N + 7) / 8, 256, 0, stream>>>(row_ptr, col, g2, dinv, b2, h2, N);

    k_starts<<<(N + BS - 1) / BS, BS, 0, stream>>>(batch, start, N, G);
    k_pool_mlp<<<G, 256, 0, stream>>>(h2, start, Wfc1, bfc1, Wfc2, bfc2, out, G);
}

// Round 2
// 430.747 us; speedup vs baseline: 2.5175x; 2.5175x over previous
//
#include <hip/hip_runtime.h>

static inline size_t align256(size_t x) { return (x + 255) & ~size_t(255); }

// ================= CSR build via two-level counting sort =================
// Buckets: 1024 dst nodes each, NBv = ceil(N/1024) <= 256.

// ---- A1: coarse bucket histogram (LDS-aggregated) ----
#define A1_EPB 16384
__global__ __launch_bounds__(256) void k_bcount(const int* __restrict__ ei,
                                                int* __restrict__ bcount,
                                                int E, int NBv) {
    __shared__ int h[256];
    int t = threadIdx.x;
    h[t] = 0;
    __syncthreads();
    int base = blockIdx.x * A1_EPB;
    int end = base + A1_EPB; if (end > E) end = E;
    for (int e = base + t; e < end; e += 256)
        atomicAdd(&h[ei[E + e] >> 10], 1);
    __syncthreads();
    if (t < NBv && h[t]) atomicAdd(&bcount[t], h[t]);
}

// ---- A0: single-block scan of bucket counts -> bases + cursors ----
__global__ void k_bscan(const int* __restrict__ bcount, int* __restrict__ bbase,
                        int* __restrict__ bcursor, int NBv, int E) {
    __shared__ int lds[256];
    int t = threadIdx.x;
    int v = (t < NBv) ? bcount[t] : 0;
    lds[t] = v;
    __syncthreads();
    for (int off = 1; off < 256; off <<= 1) {
        int x = (t >= off) ? lds[t - off] : 0;
        __syncthreads();
        lds[t] += x;
        __syncthreads();
    }
    int excl = lds[t] - v;
    if (t < NBv) { bbase[t] = excl; bcursor[t] = excl; }
    if (t == 0) bbase[NBv] = E;
}

// ---- A2: scatter edges into buckets, 4B packed (dst_local<<18 | src) ----
__global__ __launch_bounds__(256) void k_scatter(const int* __restrict__ ei,
                                                 int* __restrict__ bcursor,
                                                 unsigned* __restrict__ bdata, int E) {
    __shared__ int lcount[256];
    __shared__ int gbase[256];
    int t = threadIdx.x;
    lcount[t] = 0;
    __syncthreads();
    int chunk = blockIdx.x * 4096;
    int srcv[16], bkt[16], rank[16], dl[16];
#pragma unroll
    for (int k = 0; k < 16; ++k) {
        int e = chunk + k * 256 + t;
        bkt[k] = -1;
        if (e < E) {
            int sv = ei[e], d = ei[E + e];
            int b = d >> 10;
            srcv[k] = sv; bkt[k] = b; dl[k] = d & 1023;
            rank[k] = atomicAdd(&lcount[b], 1);
        }
    }
    __syncthreads();
    int c = lcount[t];
    gbase[t] = c ? atomicAdd(&bcursor[t], c) : 0;
    __syncthreads();
#pragma unroll
    for (int k = 0; k < 16; ++k) {
        if (bkt[k] >= 0)
            bdata[gbase[bkt[k]] + rank[k]] = ((unsigned)dl[k] << 18) | (unsigned)srcv[k];
    }
}

// ---- B: per-bucket local CSR build: hist -> scan -> row_ptr/dinv -> place col ----
__global__ __launch_bounds__(512) void k_build(const unsigned* __restrict__ bdata,
                                               const int* __restrict__ bbase,
                                               int* __restrict__ row_ptr,
                                               float* __restrict__ dinv,
                                               int* __restrict__ col,
                                               int N, int E, int NBv) {
    __shared__ int hist[1024];
    __shared__ int sums[256];
    __shared__ int curs[1024];
    int bkt = blockIdx.x;
    int t = threadIdx.x;
    int bs = bbase[bkt], be = bbase[bkt + 1];
    int node0 = bkt << 10;
    int nn = N - node0; if (nn > 1024) nn = 1024;
    for (int i = t; i < 1024; i += 512) hist[i] = 0;
    __syncthreads();
    for (int e = bs + t; e < be; e += 512)
        atomicAdd(&hist[bdata[e] >> 18], 1);
    __syncthreads();
    int v0 = 0, v1 = 0, v2 = 0, v3 = 0, s = 0;
    if (t < 256) {
        int b4 = t * 4;
        v0 = hist[b4]; v1 = hist[b4 + 1]; v2 = hist[b4 + 2]; v3 = hist[b4 + 3];
        s = v0 + v1 + v2 + v3;
        sums[t] = s;
    }
    __syncthreads();
    for (int off = 1; off < 256; off <<= 1) {
        int x = 0;
        if (t < 256 && t >= off) x = sums[t - off];
        __syncthreads();
        if (t < 256) sums[t] += x;
        __syncthreads();
    }
    if (t < 256) {
        int b4 = t * 4;
        int e0 = bs + sums[t] - s;
        int e1 = e0 + v0, e2 = e1 + v1, e3 = e2 + v2;
        curs[b4] = e0; curs[b4 + 1] = e1; curs[b4 + 2] = e2; curs[b4 + 3] = e3;
        if (b4 < nn)     { row_ptr[node0 + b4]     = e0; dinv[node0 + b4]     = rsqrtf((float)v0 + 1.f); }
        if (b4 + 1 < nn) { row_ptr[node0 + b4 + 1] = e1; dinv[node0 + b4 + 1] = rsqrtf((float)v1 + 1.f); }
        if (b4 + 2 < nn) { row_ptr[node0 + b4 + 2] = e2; dinv[node0 + b4 + 2] = rsqrtf((float)v2 + 1.f); }
        if (b4 + 3 < nn) { row_ptr[node0 + b4 + 3] = e3; dinv[node0 + b4 + 3] = rsqrtf((float)v3 + 1.f); }
    }
    if (bkt == NBv - 1 && t == 0) row_ptr[N] = E;
    __syncthreads();
    for (int e = bs + t; e < be; e += 512) {
        unsigned p = bdata[e];
        int dl = p >> 18;
        int pos = atomicAdd(&curs[dl], 1);
        col[pos] = (int)(p & 0x3FFFFu);
    }
}

// ================= feature transforms (pre-scaled by dinv) =================
__global__ void k_t1(const float* __restrict__ x, const float* __restrict__ W1,
                     const float* __restrict__ dinv, float* __restrict__ g1, int n) {
    int i = blockIdx.x * blockDim.x + threadIdx.x;
    int node = i >> 4, f = i & 15;
    if (node >= n) return;
    float x0 = x[node * 2 + 0], x1 = x[node * 2 + 1];
    g1[i] = (x0 * W1[f] + x1 * W1[16 + f]) * dinv[node];
}

__global__ void k_t2(const float* __restrict__ h1, const float* __restrict__ W2,
                     const float* __restrict__ dinv, float* __restrict__ g2, int n) {
    int i = blockIdx.x * blockDim.x + threadIdx.x;
    int node = i >> 5, of = i & 31;
    if (node >= n) return;
    const float* hr = h1 + node * 16;
    float acc = 0.f;
#pragma unroll
    for (int k = 0; k < 16; ++k) acc += hr[k] * W2[k * 32 + of];
    g2[i] = acc * dinv[node];
}

// ================= GCN aggregation =================
template <int F>
__global__ __launch_bounds__(256) void k_conv(const int* __restrict__ row_ptr,
                                              const int* __restrict__ col,
                                              const float* __restrict__ g,
                                              const float* __restrict__ dinv,
                                              const float* __restrict__ bias,
                                              float* __restrict__ out, int n) {
    constexpr int NPB = 256 / F;
    int node = blockIdx.x * NPB + threadIdx.x / F;
    int f = threadIdx.x & (F - 1);
    if (node >= n) return;
    int rs = row_ptr[node], re = row_ptr[node + 1];
    float acc = 0.f;
    int e = rs;
    for (; e + 4 <= re; e += 4) {
        int s0 = col[e], s1 = col[e + 1], s2 = col[e + 2], s3 = col[e + 3];
        float v0 = g[s0 * F + f];
        float v1 = g[s1 * F + f];
        float v2 = g[s2 * F + f];
        float v3 = g[s3 * F + f];
        acc += (v0 + v1) + (v2 + v3);
    }
    for (; e < re; ++e) acc += g[col[e] * F + f];
    acc += g[node * F + f];                     // self loop
    float v = dinv[node] * acc + bias[f];
    out[node * F + f] = fmaxf(v, 0.f);
}

// ================= pooling =================
__global__ void k_starts(const int* __restrict__ batch, int* __restrict__ start,
                         int n, int G) {
    int i = blockIdx.x * blockDim.x + threadIdx.x;
    if (i >= n) return;
    int b = batch[i];
    int bp = (i == 0) ? -1 : batch[i - 1];
    for (int k = bp + 1; k <= b; ++k) start[k] = i;
    if (i == n - 1) {
        for (int k = b + 1; k <= G; ++k) start[k] = n;
    }
}

__global__ __launch_bounds__(256) void k_pool_mlp(const float* __restrict__ h2,
                                                  const int* __restrict__ start,
                                                  const float* __restrict__ Wfc1,
                                                  const float* __restrict__ bfc1,
                                                  const float* __restrict__ Wfc2,
                                                  const float* __restrict__ bfc2,
                                                  float* __restrict__ out, int G) {
    __shared__ float lds[256];
    __shared__ float pooled[32];
    __shared__ float hidden[16];
    int g = blockIdx.x;
    if (g >= G) return;
    int s = start[g], e = start[g + 1];
    int r = threadIdx.x >> 5;
    int f = threadIdx.x & 31;
    float acc = 0.f;
    for (int i = s + r; i < e; i += 8) acc += h2[(size_t)i * 32 + f];
    lds[f * 8 + r] = acc;
    __syncthreads();
    if (threadIdx.x < 32) {
        float tt = 0.f;
#pragma unroll
        for (int k = 0; k < 8; ++k) tt += lds[threadIdx.x * 8 + k];
        float cnt = (float)(e - s);
        pooled[threadIdx.x] = tt / fmaxf(cnt, 1.0f);
    }
    __syncthreads();
    if (threadIdx.x < 16) {
        float a = bfc1[threadIdx.x];
#pragma unroll
        for (int i = 0; i < 32; ++i) a += pooled[i] * Wfc1[i * 16 + threadIdx.x];
        hidden[threadIdx.x] = fmaxf(a, 0.f);
    }
    __syncthreads();
    if (threadIdx.x == 0) {
        float a = bfc2[0];
#pragma unroll
        for (int j = 0; j < 16; ++j) a += hidden[j] * Wfc2[j];
        out[g] = a;
    }
}

extern "C" void kernel_launch(void* const* d_in, const int* in_sizes, int n_in,
                              void* d_out, int out_size, void* d_ws, size_t ws_size,
                              hipStream_t stream) {
    const float* x     = (const float*)d_in[0];
    const int*   ei    = (const int*)d_in[1];
    const int*   batch = (const int*)d_in[2];
    const float* W1    = (const float*)d_in[3];
    const float* b1    = (const float*)d_in[4];
    const float* W2    = (const float*)d_in[5];
    const float* b2    = (const float*)d_in[6];
    const float* Wfc1  = (const float*)d_in[7];
    const float* bfc1  = (const float*)d_in[8];
    const float* Wfc2  = (const float*)d_in[9];
    const float* bfc2  = (const float*)d_in[10];
    float* out = (float*)d_out;

    const int N = in_sizes[0] / 2;      // 200000
    const int E = in_sizes[1] / 2;      // 6400000
    const int G = out_size;             // 1000
    const int NBv = (N + 1023) >> 10;   // 196

    // ---- workspace layout ----
    char* ws = (char*)d_ws;
    size_t off = 0;
    float* dinv    = (float*)(ws + off); off += align256((size_t)N * 4);
    int*   row_ptr = (int*)(ws + off);   off += align256((size_t)(N + 1) * 4);
    int*   bcount  = (int*)(ws + off);   off += align256(256 * 4);
    int*   bbase   = (int*)(ws + off);   off += align256(257 * 4);
    int*   bcursor = (int*)(ws + off);   off += align256(256 * 4);
    int*   start   = (int*)(ws + off);   off += align256((size_t)(G + 1) * 4);
    int*   col     = (int*)(ws + off);   off += align256((size_t)E * 4);
    unsigned* bdata = (unsigned*)(ws + off); // E*4 bytes, aliases g2
    float* g2      = (float*)(ws + off); off += align256((size_t)N * 32 * 4);
    float* g1      = (float*)(ws + off); // N*16 floats
    float* h1      = (float*)(ws + off + (size_t)N * 16 * 4);
    float* h2      = g1;                 // aliases g1 (dead when h2 written)

    const int BS = 256;

    hipMemsetAsync(bcount, 0, 256 * 4, stream);

    k_bcount<<<(E + A1_EPB - 1) / A1_EPB, 256, 0, stream>>>(ei, bcount, E, NBv);
    k_bscan<<<1, 256, 0, stream>>>(bcount, bbase, bcursor, NBv, E);
    k_scatter<<<(E + 4095) / 4096, 256, 0, stream>>>(ei, bcursor, bdata, E);
    k_build<<<NBv, 512, 0, stream>>>(bdata, bbase, row_ptr, dinv, col, N, E, NBv);

    k_t1<<<((size_t)N * 16 + BS - 1) / BS, BS, 0, stream>>>(x, W1, dinv, g1, N);
    k_conv<16><<<(N + 15) / 16, 256, 0, stream>>>(row_ptr, col, g1, dinv, b1, h1, N);
    k_t2<<<((size_t)N * 32 + BS - 1) / BS, BS, 0, stream>>>(h1, W2, dinv, g2, N);
    k_conv<32><<<(N + 7) / 8, 256, 0, stream>>>(row_ptr, col, g2, dinv, b2, h2, N);

    k_starts<<<(N + BS - 1) / BS, BS, 0, stream>>>(batch, start, N, G);
    k_pool_mlp<<<G, 256, 0, stream>>>(h2, start, Wfc1, bfc1, Wfc2, bfc2, out, G);
}

// Round 3
// 353.495 us; speedup vs baseline: 3.0676x; 1.2185x over previous
//
#include <hip/hip_runtime.h>

static inline size_t align256(size_t x) { return (x + 255) & ~size_t(255); }
static inline size_t maxsz(size_t a, size_t b) { return a > b ? a : b; }

// ================= CSR build via two-level counting sort =================
#define A1_EPB 16384
__global__ __launch_bounds__(256) void k_bcount(const int* __restrict__ ei,
                                                int* __restrict__ bcount,
                                                int E, int NBv) {
    __shared__ int h[256];
    int t = threadIdx.x;
    h[t] = 0;
    __syncthreads();
    int base = blockIdx.x * A1_EPB;
    int end = base + A1_EPB; if (end > E) end = E;
    for (int e = base + t; e < end; e += 256)
        atomicAdd(&h[ei[E + e] >> 10], 1);
    __syncthreads();
    if (t < NBv && h[t]) atomicAdd(&bcount[t], h[t]);
}

__global__ void k_bscan(const int* __restrict__ bcount, int* __restrict__ bbase,
                        int* __restrict__ bcursor, int NBv, int E) {
    __shared__ int lds[256];
    int t = threadIdx.x;
    int v = (t < NBv) ? bcount[t] : 0;
    lds[t] = v;
    __syncthreads();
    for (int off = 1; off < 256; off <<= 1) {
        int x = (t >= off) ? lds[t - off] : 0;
        __syncthreads();
        lds[t] += x;
        __syncthreads();
    }
    int excl = lds[t] - v;
    if (t < NBv) { bbase[t] = excl; bcursor[t] = excl; }
    if (t == 0) bbase[NBv] = E;
}

__global__ __launch_bounds__(256) void k_scatter(const int* __restrict__ ei,
                                                 int* __restrict__ bcursor,
                                                 unsigned* __restrict__ bdata, int E) {
    __shared__ int lcount[256];
    __shared__ int gbase[256];
    int t = threadIdx.x;
    lcount[t] = 0;
    __syncthreads();
    int chunk = blockIdx.x * 4096;
    int srcv[16], bkt[16], rank[16], dl[16];
#pragma unroll
    for (int k = 0; k < 16; ++k) {
        int e = chunk + k * 256 + t;
        bkt[k] = -1;
        if (e < E) {
            int sv = ei[e], d = ei[E + e];
            int b = d >> 10;
            srcv[k] = sv; bkt[k] = b; dl[k] = d & 1023;
            rank[k] = atomicAdd(&lcount[b], 1);
        }
    }
    __syncthreads();
    int c = lcount[t];
    gbase[t] = c ? atomicAdd(&bcursor[t], c) : 0;
    __syncthreads();
#pragma unroll
    for (int k = 0; k < 16; ++k) {
        if (bkt[k] >= 0)
            bdata[gbase[bkt[k]] + rank[k]] = ((unsigned)dl[k] << 18) | (unsigned)srcv[k];
    }
}

__global__ __launch_bounds__(512) void k_build(const unsigned* __restrict__ bdata,
                                               const int* __restrict__ bbase,
                                               int* __restrict__ row_ptr,
                                               float* __restrict__ dinv,
                                               int* __restrict__ col,
                                               int N, int E, int NBv) {
    __shared__ int hist[1024];
    __shared__ int sums[256];
    __shared__ int curs[1024];
    int bkt = blockIdx.x;
    int t = threadIdx.x;
    int bs = bbase[bkt], be = bbase[bkt + 1];
    int node0 = bkt << 10;
    int nn = N - node0; if (nn > 1024) nn = 1024;
    for (int i = t; i < 1024; i += 512) hist[i] = 0;
    __syncthreads();
    for (int e = bs + t; e < be; e += 512)
        atomicAdd(&hist[bdata[e] >> 18], 1);
    __syncthreads();
    int v0 = 0, v1 = 0, v2 = 0, v3 = 0, s = 0;
    if (t < 256) {
        int b4 = t * 4;
        v0 = hist[b4]; v1 = hist[b4 + 1]; v2 = hist[b4 + 2]; v3 = hist[b4 + 3];
        s = v0 + v1 + v2 + v3;
        sums[t] = s;
    }
    __syncthreads();
    for (int off = 1; off < 256; off <<= 1) {
        int x = 0;
        if (t < 256 && t >= off) x = sums[t - off];
        __syncthreads();
        if (t < 256) sums[t] += x;
        __syncthreads();
    }
    if (t < 256) {
        int b4 = t * 4;
        int e0 = bs + sums[t] - s;
        int e1 = e0 + v0, e2 = e1 + v1, e3 = e2 + v2;
        curs[b4] = e0; curs[b4 + 1] = e1; curs[b4 + 2] = e2; curs[b4 + 3] = e3;
        if (b4 < nn)     { row_ptr[node0 + b4]     = e0; dinv[node0 + b4]     = rsqrtf((float)v0 + 1.f); }
        if (b4 + 1 < nn) { row_ptr[node0 + b4 + 1] = e1; dinv[node0 + b4 + 1] = rsqrtf((float)v1 + 1.f); }
        if (b4 + 2 < nn) { row_ptr[node0 + b4 + 2] = e2; dinv[node0 + b4 + 2] = rsqrtf((float)v2 + 1.f); }
        if (b4 + 3 < nn) { row_ptr[node0 + b4 + 3] = e3; dinv[node0 + b4 + 3] = rsqrtf((float)v3 + 1.f); }
    }
    if (bkt == NBv - 1 && t == 0) row_ptr[N] = E;
    __syncthreads();
    for (int e = bs + t; e < be; e += 512) {
        unsigned p = bdata[e];
        int dl = p >> 18;
        int pos = atomicAdd(&curs[dl], 1);
        col[pos] = (int)(p & 0x3FFFFu);
    }
}

// ================= conv1: aggregate-then-transform =================
// xt[n] = x[n] * dinv[n]  (2 floats)
__global__ void k_tx(const float* __restrict__ x, const float* __restrict__ dinv,
                     float2* __restrict__ xt, int n) {
    int i = blockIdx.x * blockDim.x + threadIdx.x;
    if (i >= n) return;
    float dv = dinv[i];
    xt[i] = make_float2(x[i * 2] * dv, x[i * 2 + 1] * dv);
}

// agg1[n] = dinv[n] * (sum xt[col] + xt[n])   -- one thread per node, 8B gathers
__global__ __launch_bounds__(256) void k_agg2f(const int* __restrict__ rp,
                                               const int* __restrict__ col,
                                               const float2* __restrict__ xt,
                                               const float* __restrict__ dinv,
                                               float2* __restrict__ agg, int n) {
    int i = blockIdx.x * blockDim.x + threadIdx.x;
    if (i >= n) return;
    int rs = rp[i], re = rp[i + 1];
    float a0 = 0.f, a1 = 0.f;
    int e = rs;
    for (; e + 4 <= re; e += 4) {
        int c0 = col[e], c1 = col[e + 1], c2 = col[e + 2], c3 = col[e + 3];
        float2 v0 = xt[c0], v1 = xt[c1], v2 = xt[c2], v3 = xt[c3];
        a0 += (v0.x + v1.x) + (v2.x + v3.x);
        a1 += (v0.y + v1.y) + (v2.y + v3.y);
    }
    for (; e < re; ++e) { float2 v = xt[col[e]]; a0 += v.x; a1 += v.y; }
    float2 sf = xt[i];
    a0 += sf.x; a1 += sf.y;
    float dv = dinv[i];
    agg[i] = make_float2(a0 * dv, a1 * dv);
}

// ht1[n][f] = relu(agg1[n].x*W1[0][f] + agg1[n].y*W1[1][f] + b1[f]) * dinv[n]
__global__ void k_h1t(const float2* __restrict__ agg1, const float* __restrict__ W1,
                      const float* __restrict__ b1, const float* __restrict__ dinv,
                      float* __restrict__ ht1, int n) {
    int i = blockIdx.x * blockDim.x + threadIdx.x;
    int node = i >> 4, f = i & 15;
    if (node >= n) return;
    float2 a = agg1[node];
    float v = fmaxf(a.x * W1[f] + a.y * W1[16 + f] + b1[f], 0.f);
    ht1[i] = v * dinv[node];
}

// ================= conv2: aggregate 16-wide, then 16x32 transform =================
// agg2[n][f] = dinv[n] * (sum ht1[col][f] + ht1[n][f])
__global__ __launch_bounds__(256) void k_agg16(const int* __restrict__ row_ptr,
                                               const int* __restrict__ col,
                                               const float* __restrict__ g,
                                               const float* __restrict__ dinv,
                                               float* __restrict__ agg2, int n) {
    int node = blockIdx.x * 16 + (threadIdx.x >> 4);
    int f = threadIdx.x & 15;
    if (node >= n) return;
    int rs = row_ptr[node], re = row_ptr[node + 1];
    float acc = 0.f;
    int e = rs;
    for (; e + 4 <= re; e += 4) {
        int s0 = col[e], s1 = col[e + 1], s2 = col[e + 2], s3 = col[e + 3];
        float v0 = g[s0 * 16 + f];
        float v1 = g[s1 * 16 + f];
        float v2 = g[s2 * 16 + f];
        float v3 = g[s3 * 16 + f];
        acc += (v0 + v1) + (v2 + v3);
    }
    for (; e < re; ++e) acc += g[col[e] * 16 + f];
    acc += g[node * 16 + f];
    agg2[node * 16 + f] = dinv[node] * acc;
}

// h2[n][j] = relu(sum_k agg2[n][k]*W2[k][j] + b2[j])
__global__ void k_h2(const float* __restrict__ agg2, const float* __restrict__ W2,
                     const float* __restrict__ b2, float* __restrict__ h2, int n) {
    int i = blockIdx.x * blockDim.x + threadIdx.x;
    int node = i >> 5, j = i & 31;
    if (node >= n) return;
    const float* ar = agg2 + node * 16;
    float acc = b2[j];
#pragma unroll
    for (int k = 0; k < 16; ++k) acc += ar[k] * W2[k * 32 + j];
    h2[i] = fmaxf(acc, 0.f);
}

// ================= pooling =================
__global__ void k_starts(const int* __restrict__ batch, int* __restrict__ start,
                         int n, int G) {
    int i = blockIdx.x * blockDim.x + threadIdx.x;
    if (i >= n) return;
    int b = batch[i];
    int bp = (i == 0) ? -1 : batch[i - 1];
    for (int k = bp + 1; k <= b; ++k) start[k] = i;
    if (i == n - 1) {
        for (int k = b + 1; k <= G; ++k) start[k] = n;
    }
}

__global__ __launch_bounds__(256) void k_pool_mlp(const float* __restrict__ h2,
                                                  const int* __restrict__ start,
                                                  const float* __restrict__ Wfc1,
                                                  const float* __restrict__ bfc1,
                                                  const float* __restrict__ Wfc2,
                                                  const float* __restrict__ bfc2,
                                                  float* __restrict__ out, int G) {
    __shared__ float lds[256];
    __shared__ float pooled[32];
    __shared__ float hidden[16];
    int g = blockIdx.x;
    if (g >= G) return;
    int s = start[g], e = start[g + 1];
    int r = threadIdx.x >> 5;
    int f = threadIdx.x & 31;
    float acc = 0.f;
    for (int i = s + r; i < e; i += 8) acc += h2[(size_t)i * 32 + f];
    lds[f * 8 + r] = acc;
    __syncthreads();
    if (threadIdx.x < 32) {
        float tt = 0.f;
#pragma unroll
        for (int k = 0; k < 8; ++k) tt += lds[threadIdx.x * 8 + k];
        float cnt = (float)(e - s);
        pooled[threadIdx.x] = tt / fmaxf(cnt, 1.0f);
    }
    __syncthreads();
    if (threadIdx.x < 16) {
        float a = bfc1[threadIdx.x];
#pragma unroll
        for (int i = 0; i < 32; ++i) a += pooled[i] * Wfc1[i * 16 + threadIdx.x];
        hidden[threadIdx.x] = fmaxf(a, 0.f);
    }
    __syncthreads();
    if (threadIdx.x == 0) {
        float a = bfc2[0];
#pragma unroll
        for (int j = 0; j < 16; ++j) a += hidden[j] * Wfc2[j];
        out[g] = a;
    }
}

extern "C" void kernel_launch(void* const* d_in, const int* in_sizes, int n_in,
                              void* d_out, int out_size, void* d_ws, size_t ws_size,
                              hipStream_t stream) {
    const float* x     = (const float*)d_in[0];
    const int*   ei    = (const int*)d_in[1];
    const int*   batch = (const int*)d_in[2];
    const float* W1    = (const float*)d_in[3];
    const float* b1    = (const float*)d_in[4];
    const float* W2    = (const float*)d_in[5];
    const float* b2    = (const float*)d_in[6];
    const float* Wfc1  = (const float*)d_in[7];
    const float* bfc1  = (const float*)d_in[8];
    const float* Wfc2  = (const float*)d_in[9];
    const float* bfc2  = (const float*)d_in[10];
    float* out = (float*)d_out;

    const int N = in_sizes[0] / 2;      // 200000
    const int E = in_sizes[1] / 2;      // 6400000
    const int G = out_size;             // 1000
    const int NBv = (N + 1023) >> 10;   // 196

    // ---- workspace layout (~56 MB) ----
    char* ws = (char*)d_ws;
    size_t off = 0;
    float* dinv    = (float*)(ws + off); off += align256((size_t)N * 4);
    int*   row_ptr = (int*)(ws + off);   off += align256((size_t)(N + 1) * 4);
    int*   bcount  = (int*)(ws + off);   off += align256(256 * 4);
    int*   bbase   = (int*)(ws + off);   off += align256(257 * 4);
    int*   bcursor = (int*)(ws + off);   off += align256(256 * 4);
    int*   start   = (int*)(ws + off);   off += align256((size_t)(G + 1) * 4);
    float2* xt     = (float2*)(ws + off); off += align256((size_t)N * 8);
    float2* agg1   = (float2*)(ws + off); off += align256((size_t)N * 8);
    int*   col     = (int*)(ws + off);   off += align256(maxsz((size_t)E * 4, (size_t)N * 32 * 4));
    unsigned* bdata = (unsigned*)(ws + off); off += align256(maxsz((size_t)E * 4, (size_t)N * 32 * 4));
    // after k_build, bdata region is reused:
    float* ht1  = (float*)bdata;                 // N*16 floats
    float* agg2 = (float*)bdata + (size_t)N * 16; // N*16 floats
    // after k_agg16, col region is reused:
    float* h2   = (float*)col;                   // N*32 floats

    const int BS = 256;

    hipMemsetAsync(bcount, 0, 256 * 4, stream);

    k_bcount<<<(E + A1_EPB - 1) / A1_EPB, 256, 0, stream>>>(ei, bcount, E, NBv);
    k_bscan<<<1, 256, 0, stream>>>(bcount, bbase, bcursor, NBv, E);
    k_scatter<<<(E + 4095) / 4096, 256, 0, stream>>>(ei, bcursor, bdata, E);
    k_build<<<NBv, 512, 0, stream>>>(bdata, bbase, row_ptr, dinv, col, N, E, NBv);

    k_tx<<<(N + BS - 1) / BS, BS, 0, stream>>>(x, dinv, xt, N);
    k_agg2f<<<(N + BS - 1) / BS, BS, 0, stream>>>(row_ptr, col, xt, dinv, agg1, N);
    k_h1t<<<((size_t)N * 16 + BS - 1) / BS, BS, 0, stream>>>(agg1, W1, b1, dinv, ht1, N);
    k_agg16<<<(N + 15) / 16, 256, 0, stream>>>(row_ptr, col, ht1, dinv, agg2, N);
    k_h2<<<((size_t)N * 32 + BS - 1) / BS, BS, 0, stream>>>(agg2, W2, b2, h2, N);

    k_starts<<<(N + BS - 1) / BS, BS, 0, stream>>>(batch, start, N, G);
    k_pool_mlp<<<G, 256, 0, stream>>>(h2, start, Wfc1, bfc1, Wfc2, bfc2, out, G);
}

// Round 4
// 312.874 us; speedup vs baseline: 3.4659x; 1.1298x over previous
//
#include <hip/hip_runtime.h>
#include <hip/hip_fp16.h>

static inline size_t align256(size_t x) { return (x + 255) & ~size_t(255); }

// ================= CSR build via two-level counting sort =================
#define A1_EPB 16384
__global__ __launch_bounds__(256) void k_bcount(const int* __restrict__ ei,
                                                int* __restrict__ bcount,
                                                int E, int NBv) {
    __shared__ int h[256];
    int t = threadIdx.x;
    h[t] = 0;
    __syncthreads();
    int base = blockIdx.x * A1_EPB;
    int end = base + A1_EPB; if (end > E) end = E;
    for (int e = base + t; e < end; e += 256)
        atomicAdd(&h[ei[E + e] >> 10], 1);
    __syncthreads();
    if (t < NBv && h[t]) atomicAdd(&bcount[t], h[t]);
}

__global__ void k_bscan(const int* __restrict__ bcount, int* __restrict__ bbase,
                        int* __restrict__ bcursor, int NBv, int E) {
    __shared__ int lds[256];
    int t = threadIdx.x;
    int v = (t < NBv) ? bcount[t] : 0;
    lds[t] = v;
    __syncthreads();
    for (int off = 1; off < 256; off <<= 1) {
        int x = (t >= off) ? lds[t - off] : 0;
        __syncthreads();
        lds[t] += x;
        __syncthreads();
    }
    int excl = lds[t] - v;
    if (t < NBv) { bbase[t] = excl; bcursor[t] = excl; }
    if (t == 0) bbase[NBv] = E;
}

__global__ __launch_bounds__(256) void k_scatter(const int* __restrict__ ei,
                                                 int* __restrict__ bcursor,
                                                 unsigned* __restrict__ bdata, int E) {
    __shared__ int lcount[256];
    __shared__ int gbase[256];
    int t = threadIdx.x;
    lcount[t] = 0;
    __syncthreads();
    int chunk = blockIdx.x * 4096;
    int srcv[16], bkt[16], rank[16], dl[16];
#pragma unroll
    for (int k = 0; k < 16; ++k) {
        int e = chunk + k * 256 + t;
        bkt[k] = -1;
        if (e < E) {
            int sv = ei[e], d = ei[E + e];
            int b = d >> 10;
            srcv[k] = sv; bkt[k] = b; dl[k] = d & 1023;
            rank[k] = atomicAdd(&lcount[b], 1);
        }
    }
    __syncthreads();
    int c = lcount[t];
    gbase[t] = c ? atomicAdd(&bcursor[t], c) : 0;
    __syncthreads();
#pragma unroll
    for (int k = 0; k < 16; ++k) {
        if (bkt[k] >= 0)
            bdata[gbase[bkt[k]] + rank[k]] = ((unsigned)dl[k] << 18) | (unsigned)srcv[k];
    }
}

__global__ __launch_bounds__(512) void k_build(const unsigned* __restrict__ bdata,
                                               const int* __restrict__ bbase,
                                               int* __restrict__ row_ptr,
                                               float* __restrict__ dinv,
                                               int* __restrict__ col,
                                               int N, int E, int NBv) {
    __shared__ int hist[1024];
    __shared__ int sums[256];
    __shared__ int curs[1024];
    int bkt = blockIdx.x;
    int t = threadIdx.x;
    int bs = bbase[bkt], be = bbase[bkt + 1];
    int node0 = bkt << 10;
    int nn = N - node0; if (nn > 1024) nn = 1024;
    for (int i = t; i < 1024; i += 512) hist[i] = 0;
    __syncthreads();
    for (int e = bs + t; e < be; e += 512)
        atomicAdd(&hist[bdata[e] >> 18], 1);
    __syncthreads();
    int v0 = 0, v1 = 0, v2 = 0, v3 = 0, s = 0;
    if (t < 256) {
        int b4 = t * 4;
        v0 = hist[b4]; v1 = hist[b4 + 1]; v2 = hist[b4 + 2]; v3 = hist[b4 + 3];
        s = v0 + v1 + v2 + v3;
        sums[t] = s;
    }
    __syncthreads();
    for (int off = 1; off < 256; off <<= 1) {
        int x = 0;
        if (t < 256 && t >= off) x = sums[t - off];
        __syncthreads();
        if (t < 256) sums[t] += x;
        __syncthreads();
    }
    if (t < 256) {
        int b4 = t * 4;
        int e0 = bs + sums[t] - s;
        int e1 = e0 + v0, e2 = e1 + v1, e3 = e2 + v2;
        curs[b4] = e0; curs[b4 + 1] = e1; curs[b4 + 2] = e2; curs[b4 + 3] = e3;
        if (b4 < nn)     { row_ptr[node0 + b4]     = e0; dinv[node0 + b4]     = rsqrtf((float)v0 + 1.f); }
        if (b4 + 1 < nn) { row_ptr[node0 + b4 + 1] = e1; dinv[node0 + b4 + 1] = rsqrtf((float)v1 + 1.f); }
        if (b4 + 2 < nn) { row_ptr[node0 + b4 + 2] = e2; dinv[node0 + b4 + 2] = rsqrtf((float)v2 + 1.f); }
        if (b4 + 3 < nn) { row_ptr[node0 + b4 + 3] = e3; dinv[node0 + b4 + 3] = rsqrtf((float)v3 + 1.f); }
    }
    if (bkt == NBv - 1 && t == 0) row_ptr[N] = E;
    __syncthreads();
    for (int e = bs + t; e < be; e += 512) {
        unsigned p = bdata[e];
        int dl = p >> 18;
        int pos = atomicAdd(&curs[dl], 1);
        col[pos] = (int)(p & 0x3FFFFu);
    }
}

// ================= conv1 (fused): agg(x*dinv) -> W1+b1+relu -> *dinv -> fp16 =================
__global__ void k_tx(const float* __restrict__ x, const float* __restrict__ dinv,
                     float2* __restrict__ xt, int n) {
    int i = blockIdx.x * blockDim.x + threadIdx.x;
    if (i >= n) return;
    float dv = dinv[i];
    xt[i] = make_float2(x[i * 2] * dv, x[i * 2 + 1] * dv);
}

__global__ __launch_bounds__(256) void k_conv1_fused(const int* __restrict__ rp,
                                                     const int* __restrict__ col,
                                                     const float2* __restrict__ xt,
                                                     const float* __restrict__ dinv,
                                                     const float* __restrict__ W1,
                                                     const float* __restrict__ b1,
                                                     __half2* __restrict__ ht2, int n) {
    int i = blockIdx.x * blockDim.x + threadIdx.x;
    if (i >= n) return;
    int rs = rp[i], re = rp[i + 1];
    float a0 = 0.f, a1 = 0.f;
    int e = rs;
    for (; e + 4 <= re; e += 4) {
        int c0 = col[e], c1 = col[e + 1], c2 = col[e + 2], c3 = col[e + 3];
        float2 v0 = xt[c0], v1 = xt[c1], v2 = xt[c2], v3 = xt[c3];
        a0 += (v0.x + v1.x) + (v2.x + v3.x);
        a1 += (v0.y + v1.y) + (v2.y + v3.y);
    }
    for (; e < re; ++e) { float2 v = xt[col[e]]; a0 += v.x; a1 += v.y; }
    float2 sf = xt[i];
    a0 += sf.x; a1 += sf.y;
    float dv = dinv[i];
    a0 *= dv; a1 *= dv;
    __half2 hv[8];
#pragma unroll
    for (int f2 = 0; f2 < 8; ++f2) {
        float v0 = fmaxf(a0 * W1[2 * f2]     + a1 * W1[16 + 2 * f2]     + b1[2 * f2],     0.f) * dv;
        float v1 = fmaxf(a0 * W1[2 * f2 + 1] + a1 * W1[16 + 2 * f2 + 1] + b1[2 * f2 + 1], 0.f) * dv;
        hv[f2] = __floats2half2_rn(v0, v1);
    }
    uint4* dst = (uint4*)(ht2 + (size_t)i * 8);
    dst[0] = *reinterpret_cast<uint4*>(&hv[0]);
    dst[1] = *reinterpret_cast<uint4*>(&hv[4]);
}

// ================= conv2 (fused): fp16 agg -> W2+b2+relu -> segmented pool =================
__global__ __launch_bounds__(256) void k_conv2_fused(const int* __restrict__ rp,
                                                     const int* __restrict__ col,
                                                     const __half2* __restrict__ ht2,
                                                     const float* __restrict__ dinv,
                                                     const float* __restrict__ W2,
                                                     const float* __restrict__ b2,
                                                     const int* __restrict__ batch,
                                                     float* __restrict__ gsum, int N) {
    __shared__ float aggs[32][17];
    __shared__ float h2s[32][33];
    __shared__ float w2s[512];   // [16][32] row-major
    __shared__ float b2s[32];
    __shared__ int   bids[32];
    int t = threadIdx.x;
    if (t < 128) ((float4*)w2s)[t] = ((const float4*)W2)[t];
    if (t < 32)  b2s[t] = b2[t];
    int node0 = blockIdx.x * 32;
    if (t < 32)  bids[t] = (node0 + t < N) ? batch[node0 + t] : -1;

    int nl = t >> 3;       // 0..31 node within block
    int fp = t & 7;        // half2 index within 32B row
    int node = node0 + nl;
    bool valid = node < N;
    int rs = valid ? rp[node] : 0;
    int re = valid ? rp[node + 1] : 0;
    float ax = 0.f, ay = 0.f;
    int e = rs;
    for (; e + 8 <= re; e += 8) {
        int c0 = col[e],     c1 = col[e + 1], c2 = col[e + 2], c3 = col[e + 3];
        int c4 = col[e + 4], c5 = col[e + 5], c6 = col[e + 6], c7 = col[e + 7];
        float2 f0 = __half22float2(ht2[(size_t)c0 * 8 + fp]);
        float2 f1 = __half22float2(ht2[(size_t)c1 * 8 + fp]);
        float2 f2 = __half22float2(ht2[(size_t)c2 * 8 + fp]);
        float2 f3 = __half22float2(ht2[(size_t)c3 * 8 + fp]);
        float2 f4 = __half22float2(ht2[(size_t)c4 * 8 + fp]);
        float2 f5 = __half22float2(ht2[(size_t)c5 * 8 + fp]);
        float2 f6 = __half22float2(ht2[(size_t)c6 * 8 + fp]);
        float2 f7 = __half22float2(ht2[(size_t)c7 * 8 + fp]);
        ax += ((f0.x + f1.x) + (f2.x + f3.x)) + ((f4.x + f5.x) + (f6.x + f7.x));
        ay += ((f0.y + f1.y) + (f2.y + f3.y)) + ((f4.y + f5.y) + (f6.y + f7.y));
    }
    for (; e < re; ++e) {
        float2 f = __half22float2(ht2[(size_t)col[e] * 8 + fp]);
        ax += f.x; ay += f.y;
    }
    if (valid) {
        float2 s = __half22float2(ht2[(size_t)node * 8 + fp]);
        ax += s.x; ay += s.y;
    }
    float dv = valid ? dinv[node] : 0.f;
    aggs[nl][2 * fp]     = ax * dv;
    aggs[nl][2 * fp + 1] = ay * dv;
    __syncthreads();

    // transform: thread -> (node = t>>3, 4 outputs at jq)
    {
        int nl2 = t >> 3;
        int jq = (t & 7) * 4;
        float o0 = b2s[jq], o1 = b2s[jq + 1], o2 = b2s[jq + 2], o3 = b2s[jq + 3];
#pragma unroll
        for (int k = 0; k < 16; ++k) {
            float a = aggs[nl2][k];
            o0 += a * w2s[k * 32 + jq];
            o1 += a * w2s[k * 32 + jq + 1];
            o2 += a * w2s[k * 32 + jq + 2];
            o3 += a * w2s[k * 32 + jq + 3];
        }
        h2s[nl2][jq]     = fmaxf(o0, 0.f);
        h2s[nl2][jq + 1] = fmaxf(o1, 0.f);
        h2s[nl2][jq + 2] = fmaxf(o2, 0.f);
        h2s[nl2][jq + 3] = fmaxf(o3, 0.f);
    }
    __syncthreads();

    // segmented pooling into gsum (batch sorted -> few atomics)
    if (t < 64) {
        int j = t & 31, half = t >> 5;
        int nbeg = half * 16, nend = nbeg + 16;
        float acc = 0.f;
        int cur = bids[nbeg];
        for (int n2 = nbeg; n2 < nend; ++n2) {
            int b = bids[n2];
            if (b != cur) {
                if (cur >= 0) atomicAdd(&gsum[(size_t)cur * 32 + j], acc);
                acc = 0.f; cur = b;
            }
            if (b >= 0) acc += h2s[n2][j];
        }
        if (cur >= 0) atomicAdd(&gsum[(size_t)cur * 32 + j], acc);
    }
}

// ================= pooling bounds + final MLP =================
__global__ void k_starts(const int* __restrict__ batch, int* __restrict__ start,
                         int n, int G) {
    int i = blockIdx.x * blockDim.x + threadIdx.x;
    if (i >= n) return;
    int b = batch[i];
    int bp = (i == 0) ? -1 : batch[i - 1];
    for (int k = bp + 1; k <= b; ++k) start[k] = i;
    if (i == n - 1) {
        for (int k = b + 1; k <= G; ++k) start[k] = n;
    }
}

__global__ void k_final(const float* __restrict__ gsum, const int* __restrict__ start,
                        const float* __restrict__ Wfc1, const float* __restrict__ bfc1,
                        const float* __restrict__ Wfc2, const float* __restrict__ bfc2,
                        float* __restrict__ out, int G) {
    int g = blockIdx.x * blockDim.x + threadIdx.x;
    if (g >= G) return;
    float cnt = (float)(start[g + 1] - start[g]);
    float inv = 1.f / fmaxf(cnt, 1.f);
    float p[32];
#pragma unroll
    for (int i = 0; i < 32; ++i) p[i] = gsum[(size_t)g * 32 + i] * inv;
    float o = bfc2[0];
#pragma unroll
    for (int j = 0; j < 16; ++j) {
        float a = bfc1[j];
#pragma unroll
        for (int i = 0; i < 32; ++i) a += p[i] * Wfc1[i * 16 + j];
        o += fmaxf(a, 0.f) * Wfc2[j];
    }
    out[g] = o;
}

extern "C" void kernel_launch(void* const* d_in, const int* in_sizes, int n_in,
                              void* d_out, int out_size, void* d_ws, size_t ws_size,
                              hipStream_t stream) {
    const float* x     = (const float*)d_in[0];
    const int*   ei    = (const int*)d_in[1];
    const int*   batch = (const int*)d_in[2];
    const float* W1    = (const float*)d_in[3];
    const float* b1    = (const float*)d_in[4];
    const float* W2    = (const float*)d_in[5];
    const float* b2    = (const float*)d_in[6];
    const float* Wfc1  = (const float*)d_in[7];
    const float* bfc1  = (const float*)d_in[8];
    const float* Wfc2  = (const float*)d_in[9];
    const float* bfc2  = (const float*)d_in[10];
    float* out = (float*)d_out;

    const int N = in_sizes[0] / 2;      // 200000
    const int E = in_sizes[1] / 2;      // 6400000
    const int G = out_size;             // 1000
    const int NBv = (N + 1023) >> 10;   // 196

    // ---- workspace layout (~61 MB) ----
    char* ws = (char*)d_ws;
    size_t off = 0;
    float* dinv    = (float*)(ws + off); off += align256((size_t)N * 4);
    int*   row_ptr = (int*)(ws + off);   off += align256((size_t)(N + 1) * 4);
    int*   bcount  = (int*)(ws + off);   off += align256(256 * 4);
    int*   bbase   = (int*)(ws + off);   off += align256(257 * 4);
    int*   bcursor = (int*)(ws + off);   off += align256(256 * 4);
    int*   start   = (int*)(ws + off);   off += align256((size_t)(G + 1) * 4);
    float* gsum    = (float*)(ws + off); off += align256((size_t)G * 32 * 4);
    float2* xt     = (float2*)(ws + off); off += align256((size_t)N * 8);
    __half2* ht2   = (__half2*)(ws + off); off += align256((size_t)N * 32);
    int*   col     = (int*)(ws + off);   off += align256((size_t)E * 4);
    unsigned* bdata = (unsigned*)(ws + off); off += align256((size_t)E * 4);

    const int BS = 256;

    hipMemsetAsync(bcount, 0, 256 * 4, stream);
    hipMemsetAsync(gsum, 0, (size_t)G * 32 * 4, stream);

    k_bcount<<<(E + A1_EPB - 1) / A1_EPB, 256, 0, stream>>>(ei, bcount, E, NBv);
    k_bscan<<<1, 256, 0, stream>>>(bcount, bbase, bcursor, NBv, E);
    k_scatter<<<(E + 4095) / 4096, 256, 0, stream>>>(ei, bcursor, bdata, E);
    k_build<<<NBv, 512, 0, stream>>>(bdata, bbase, row_ptr, dinv, col, N, E, NBv);

    k_tx<<<(N + BS - 1) / BS, BS, 0, stream>>>(x, dinv, xt, N);
    k_conv1_fused<<<(N + BS - 1) / BS, BS, 0, stream>>>(row_ptr, col, xt, dinv, W1, b1, ht2, N);
    k_conv2_fused<<<(N + 31) / 32, 256, 0, stream>>>(row_ptr, col, ht2, dinv, W2, b2, batch, gsum, N);

    k_starts<<<(N + BS - 1) / BS, BS, 0, stream>>>(batch, start, N, G);
    k_final<<<(G + BS - 1) / BS, BS, 0, stream>>>(gsum, start, Wfc1, bfc1, Wfc2, bfc2, out, G);
}